// Round 1
// baseline (657.709 us; speedup 1.0000x reference)
//
#include <hip/hip_runtime.h>

// ---------------------------------------------------------------------------
// CellVGAE GCN encoder: x -> GCN(512,128)+ReLU -> GCN(128,128)+ReLU
//                         -> {GCN(128,64) mean, GCN(128,64) log_std}
// A_norm = D^-1/2 (A + I) D^-1/2 over dst-indegree.
// Strategy: transform-then-propagate (like reference). CSR by dst built per
// launch (ws is re-poisoned). f32 everywhere this round.
// ---------------------------------------------------------------------------

// ---- mode detect: is edge_index int64 (1) or int32 (0)? -------------------
// If int64 little-endian with values < 2^31, high words (odd 32-bit indices)
// of the first 1024 values are all zero. If int32 random in [0,50000), odds of
// 1024 zeros are ~0. Reads only first 8KB (safe in both layouts).
__global__ void detect_mode_kernel(const int* __restrict__ ew, int* __restrict__ mode_p) {
    __shared__ int flag;
    if (threadIdx.x == 0) flag = 0;
    __syncthreads();
    int nz = 0;
    for (int i = threadIdx.x; i < 1024; i += 256)
        nz |= (ew[2 * i + 1] != 0);
    if (nz) atomicOr(&flag, 1);
    __syncthreads();
    if (threadIdx.x == 0) *mode_p = flag ? 0 : 1;   // 1 = int64, 0 = int32
}

__device__ __forceinline__ int load_src(const int* ew, int mode, int e, int E) {
    return mode ? ew[2 * e] : ew[e];
}
__device__ __forceinline__ int load_dst(const int* ew, int mode, int e, int E) {
    return mode ? ew[2 * E + 2 * e] : ew[E + e];
}

// ---- degree count ---------------------------------------------------------
__global__ void deg_kernel(const int* __restrict__ ew, const int* __restrict__ mode_p,
                           int* __restrict__ deg, int E) {
    int e = blockIdx.x * blockDim.x + threadIdx.x;
    if (e >= E) return;
    int mode = *mode_p;
    int d = load_dst(ew, mode, e, E);
    atomicAdd(&deg[d], 1);
}

// ---- dis = rsqrt(deg + 1)  (self-loop included) ---------------------------
__global__ void dis_kernel(const int* __restrict__ deg, float* __restrict__ dis, int N) {
    int v = blockIdx.x * blockDim.x + threadIdx.x;
    if (v >= N) return;
    dis[v] = rsqrtf((float)deg[v] + 1.0f);
}

// ---- exclusive scan over deg -> rowptr (3-kernel) -------------------------
__global__ void scan_block_kernel(const int* __restrict__ deg, int* __restrict__ rowptr,
                                  int* __restrict__ aux, int N) {
    __shared__ int s[256];
    int i = blockIdx.x * 256 + threadIdx.x;
    int v = (i < N) ? deg[i] : 0;
    s[threadIdx.x] = v;
    __syncthreads();
    for (int off = 1; off < 256; off <<= 1) {
        int t = (threadIdx.x >= off) ? s[threadIdx.x - off] : 0;
        __syncthreads();
        s[threadIdx.x] += t;
        __syncthreads();
    }
    if (i < N) rowptr[i] = s[threadIdx.x] - v;        // exclusive within block
    if (threadIdx.x == 255) aux[blockIdx.x] = s[255]; // block total
}

__global__ void scan_aux_kernel(int* __restrict__ aux, int nb) {
    __shared__ int s[256];
    int i = threadIdx.x;
    int v = (i < nb) ? aux[i] : 0;
    s[i] = v;
    __syncthreads();
    for (int off = 1; off < 256; off <<= 1) {
        int t = (i >= off) ? s[i - off] : 0;
        __syncthreads();
        s[i] += t;
        __syncthreads();
    }
    if (i < nb) aux[i] = s[i] - v;                    // exclusive
}

__global__ void add_offsets_kernel(int* __restrict__ rowptr, const int* __restrict__ aux,
                                   int N, int E) {
    int i = blockIdx.x * 256 + threadIdx.x;
    if (i < N) rowptr[i] += aux[i >> 8];
    if (i == 0) rowptr[N] = E;
}

// ---- CSR fill: csr_src + precomputed edge weight --------------------------
__global__ void fill_csr_kernel(const int* __restrict__ ew, const int* __restrict__ mode_p,
                                const int* __restrict__ rowptr, int* __restrict__ cursor,
                                const float* __restrict__ dis,
                                int* __restrict__ csr_src, float* __restrict__ csr_w, int E) {
    int e = blockIdx.x * blockDim.x + threadIdx.x;
    if (e >= E) return;
    int mode = *mode_p;
    int s = load_src(ew, mode, e, E);
    int d = load_dst(ew, mode, e, E);
    int pos = rowptr[d] + atomicAdd(&cursor[d], 1);
    csr_src[pos] = s;
    csr_w[pos] = dis[s] * dis[d];
}

// ---- pack [Wm | Ws] into one 128x128 --------------------------------------
__global__ void pack_w_kernel(const float* __restrict__ Wm, const float* __restrict__ Ws,
                              float* __restrict__ Wcat) {
    int idx = blockIdx.x * blockDim.x + threadIdx.x; // 128*128
    if (idx >= 128 * 128) return;
    int k = idx >> 7, j = idx & 127;
    Wcat[idx] = (j < 64) ? Wm[k * 64 + j] : Ws[k * 64 + (j - 64)];
}

// ---- f32 tiled GEMM: C[N x M] = A[N x K] @ B[K x M], M,K % 16 == 0 --------
__global__ __launch_bounds__(256) void gemm_f32(const float* __restrict__ A,
                                                const float* __restrict__ B,
                                                float* __restrict__ C,
                                                int N, int K, int M) {
    __shared__ float As[16][65];
    __shared__ float Bs[16][64];
    const int tid = threadIdx.x;
    const int tx = tid & 15, ty = tid >> 4;
    const int row0 = blockIdx.y * 64;
    const int col0 = blockIdx.x * 64;
    float c[4][4] = {};
    const int arow = tid >> 2;        // 0..63
    const int acol4 = (tid & 3) * 4;  // 0,4,8,12
    const int brow = tid >> 4;        // 0..15
    const int bcol4 = (tid & 15) * 4; // 0..60

    for (int k0 = 0; k0 < K; k0 += 16) {
        float4 av = make_float4(0.f, 0.f, 0.f, 0.f);
        int ar = row0 + arow;
        if (ar < N) av = *(const float4*)&A[(size_t)ar * K + k0 + acol4];
        As[acol4 + 0][arow] = av.x;
        As[acol4 + 1][arow] = av.y;
        As[acol4 + 2][arow] = av.z;
        As[acol4 + 3][arow] = av.w;
        *(float4*)&Bs[brow][bcol4] = *(const float4*)&B[(size_t)(k0 + brow) * M + col0 + bcol4];
        __syncthreads();
#pragma unroll
        for (int kk = 0; kk < 16; ++kk) {
            float a[4], b[4];
#pragma unroll
            for (int i = 0; i < 4; ++i) a[i] = As[kk][ty * 4 + i];
#pragma unroll
            for (int j = 0; j < 4; ++j) b[j] = Bs[kk][tx * 4 + j];
#pragma unroll
            for (int i = 0; i < 4; ++i)
#pragma unroll
                for (int j = 0; j < 4; ++j) c[i][j] += a[i] * b[j];
        }
        __syncthreads();
    }
#pragma unroll
    for (int i = 0; i < 4; ++i) {
        int r = row0 + ty * 4 + i;
        if (r < N)
            *(float4*)&C[(size_t)r * M + col0 + tx * 4] =
                make_float4(c[i][0], c[i][1], c[i][2], c[i][3]);
    }
}

// ---- propagate (one wave per node, 128 feats = 2/lane), +bias, opt ReLU ---
__global__ __launch_bounds__(256) void propagate_kernel(
    const float* __restrict__ h, const int* __restrict__ rowptr,
    const int* __restrict__ csr_src, const float* __restrict__ csr_w,
    const float* __restrict__ dis, const float* __restrict__ bias,
    float* __restrict__ out, int N, int do_relu) {
    int wave = (blockIdx.x * 256 + threadIdx.x) >> 6;
    int lane = threadIdx.x & 63;
    if (wave >= N) return;
    int v = wave;
    int f = lane * 2;
    float ax = 0.f, ay = 0.f;
    int beg = rowptr[v], end = rowptr[v + 1];
    for (int i = beg; i < end; ++i) {
        int s = csr_src[i];
        float w = csr_w[i];
        float2 hv = *(const float2*)&h[(size_t)s * 128 + f];
        ax += w * hv.x;
        ay += w * hv.y;
    }
    float dv = dis[v];
    float2 hv = *(const float2*)&h[(size_t)v * 128 + f];
    ax += dv * dv * hv.x;
    ay += dv * dv * hv.y;
    ax += bias[f];
    ay += bias[f + 1];
    if (do_relu) { ax = fmaxf(ax, 0.f); ay = fmaxf(ay, 0.f); }
    *(float2*)&out[(size_t)v * 128 + f] = make_float2(ax, ay);
}

// ---- final propagate: split into z_mean / z_log_std, +bm/+bs, no ReLU -----
__global__ __launch_bounds__(256) void propagate_final_kernel(
    const float* __restrict__ h, const int* __restrict__ rowptr,
    const int* __restrict__ csr_src, const float* __restrict__ csr_w,
    const float* __restrict__ dis, const float* __restrict__ bm,
    const float* __restrict__ bs, float* __restrict__ out, int N) {
    int wave = (blockIdx.x * 256 + threadIdx.x) >> 6;
    int lane = threadIdx.x & 63;
    if (wave >= N) return;
    int v = wave;
    int f = lane * 2;   // pairs never straddle the 64-col boundary (f even)
    float ax = 0.f, ay = 0.f;
    int beg = rowptr[v], end = rowptr[v + 1];
    for (int i = beg; i < end; ++i) {
        int s = csr_src[i];
        float w = csr_w[i];
        float2 hv = *(const float2*)&h[(size_t)s * 128 + f];
        ax += w * hv.x;
        ay += w * hv.y;
    }
    float dv = dis[v];
    float2 hv = *(const float2*)&h[(size_t)v * 128 + f];
    ax += dv * dv * hv.x;
    ay += dv * dv * hv.y;
    if (f < 64) {
        *(float2*)&out[(size_t)v * 64 + f] = make_float2(ax + bm[f], ay + bm[f + 1]);
    } else {
        int g = f - 64;
        *(float2*)&out[(size_t)N * 64 + (size_t)v * 64 + g] =
            make_float2(ax + bs[g], ay + bs[g + 1]);
    }
}

extern "C" void kernel_launch(void* const* d_in, const int* in_sizes, int n_in,
                              void* d_out, int out_size, void* d_ws, size_t ws_size,
                              hipStream_t stream) {
    const float* x  = (const float*)d_in[0];
    const int*   ew = (const int*)d_in[1];   // edge_index words (int32 or int64; detected)
    const float* W1 = (const float*)d_in[2];
    const float* b1 = (const float*)d_in[3];
    const float* W2 = (const float*)d_in[4];
    const float* b2 = (const float*)d_in[5];
    const float* Wm = (const float*)d_in[6];
    const float* bm = (const float*)d_in[7];
    const float* Ws = (const float*)d_in[8];
    const float* bs = (const float*)d_in[9];
    float* out = (float*)d_out;

    const int IN = 512, H = 128;
    const int N = in_sizes[0] / IN;     // 50000
    const int E = in_sizes[1] / 2;      // 800000

    // ---- workspace layout (256B aligned chunks) ----
    char* base = (char*)d_ws;
    size_t off = 0;
    auto alloc = [&](size_t bytes) -> char* {
        char* p = base + off;
        off = (off + bytes + 255) & ~(size_t)255;
        return p;
    };
    int*   mode_p  = (int*)  alloc(4);
    int*   deg     = (int*)  alloc((size_t)N * 4);
    int*   cursor  = (int*)  alloc((size_t)N * 4);
    float* dis     = (float*)alloc((size_t)N * 4);
    int*   rowptr  = (int*)  alloc((size_t)(N + 1) * 4);
    int*   aux     = (int*)  alloc(256 * 4);
    int*   csr_src = (int*)  alloc((size_t)E * 4);
    float* csr_w   = (float*)alloc((size_t)E * 4);
    float* Wcat    = (float*)alloc((size_t)H * H * 4);
    float* hA      = (float*)alloc((size_t)N * H * 4);  // GEMM outputs
    float* hB      = (float*)alloc((size_t)N * H * 4);  // propagate outputs
    (void)ws_size; (void)n_in; (void)out_size;

    hipMemsetAsync(deg, 0, (size_t)N * 4, stream);
    hipMemsetAsync(cursor, 0, (size_t)N * 4, stream);

    const int eblocks = (E + 255) / 256;
    const int nblocks = (N + 255) / 256;   // 196

    detect_mode_kernel<<<1, 256, 0, stream>>>(ew, mode_p);
    deg_kernel<<<eblocks, 256, 0, stream>>>(ew, mode_p, deg, E);
    dis_kernel<<<nblocks, 256, 0, stream>>>(deg, dis, N);
    scan_block_kernel<<<nblocks, 256, 0, stream>>>(deg, rowptr, aux, N);
    scan_aux_kernel<<<1, 256, 0, stream>>>(aux, nblocks);
    add_offsets_kernel<<<nblocks, 256, 0, stream>>>(rowptr, aux, N, E);
    fill_csr_kernel<<<eblocks, 256, 0, stream>>>(ew, mode_p, rowptr, cursor, dis,
                                                 csr_src, csr_w, E);
    pack_w_kernel<<<(128 * 128 + 255) / 256, 256, 0, stream>>>(Wm, Ws, Wcat);

    dim3 g1(H / 64, (N + 63) / 64);
    const int pblocks = (N * 64 + 255) / 256;  // 4 waves/block, 1 wave/node

    // layer 1: h = relu(prop(x@W1) + b1)
    gemm_f32<<<g1, 256, 0, stream>>>(x, W1, hA, N, IN, H);
    propagate_kernel<<<pblocks, 256, 0, stream>>>(hA, rowptr, csr_src, csr_w, dis,
                                                  b1, hB, N, 1);
    // layer 2: h = relu(prop(h@W2) + b2)
    gemm_f32<<<g1, 256, 0, stream>>>(hB, W2, hA, N, H, H);
    propagate_kernel<<<pblocks, 256, 0, stream>>>(hA, rowptr, csr_src, csr_w, dis,
                                                  b2, hB, N, 1);
    // heads: [z_mean | z_log_std] = prop(h@[Wm|Ws]) + [bm|bs]
    gemm_f32<<<g1, 256, 0, stream>>>(hB, Wcat, hA, N, H, H);
    propagate_final_kernel<<<pblocks, 256, 0, stream>>>(hA, rowptr, csr_src, csr_w, dis,
                                                        bm, bs, out, N);
}

// Round 3
// 586.388 us; speedup vs baseline: 1.1216x; 1.1216x over previous
//
#include <hip/hip_runtime.h>

// ---------------------------------------------------------------------------
// CellVGAE GCN encoder: x -> GCN(512,128)+ReLU -> GCN(128,128)+ReLU
//                         -> {GCN(128,64) mean, GCN(128,64) log_std}
// Round 3: same MFMA split-bf16 GEMM as round 2 (validated, absmax 1.95e-3),
// but workspace cut to 55.2 MB (< round-1-proven 58.47 MB):
//   - W-split buffers overlaid on deg/cursor (dead after CSR build)
//   - csr_w dropped; edge weight dis[s]*dis[v] computed on the fly (uniform)
// Round-2 post-timing divergence was diagnosed as d_ws overflow corrupting
// the harness's pristine input copies.
// ---------------------------------------------------------------------------

using u16 = unsigned short;
typedef __attribute__((ext_vector_type(8))) short short8;
typedef __attribute__((ext_vector_type(4))) float f32x4;

__device__ __forceinline__ void split_bf16(float f, u16& hi, u16& lo) {
    unsigned b = __float_as_uint(f);
    hi = (u16)(b >> 16);
    float rem = f - __uint_as_float(b & 0xFFFF0000u);
    lo = (u16)(__float_as_uint(rem) >> 16);
}

// ---- mode detect: is edge_index int64 (1) or int32 (0)? -------------------
__global__ void detect_mode_kernel(const int* __restrict__ ew, int* __restrict__ mode_p) {
    __shared__ int flag;
    if (threadIdx.x == 0) flag = 0;
    __syncthreads();
    int nz = 0;
    for (int i = threadIdx.x; i < 1024; i += 256)
        nz |= (ew[2 * i + 1] != 0);
    if (nz) atomicOr(&flag, 1);
    __syncthreads();
    if (threadIdx.x == 0) *mode_p = flag ? 0 : 1;   // 1 = int64, 0 = int32
}

__device__ __forceinline__ int load_src(const int* ew, int mode, int e, int E) {
    return mode ? ew[2 * e] : ew[e];
}
__device__ __forceinline__ int load_dst(const int* ew, int mode, int e, int E) {
    return mode ? ew[2 * E + 2 * e] : ew[E + e];
}

// ---- degree count ---------------------------------------------------------
__global__ void deg_kernel(const int* __restrict__ ew, const int* __restrict__ mode_p,
                           int* __restrict__ deg, int E) {
    int e = blockIdx.x * blockDim.x + threadIdx.x;
    if (e >= E) return;
    int mode = *mode_p;
    int d = load_dst(ew, mode, e, E);
    atomicAdd(&deg[d], 1);
}

// ---- dis = rsqrt(deg + 1)  (self-loop included) ---------------------------
__global__ void dis_kernel(const int* __restrict__ deg, float* __restrict__ dis, int N) {
    int v = blockIdx.x * blockDim.x + threadIdx.x;
    if (v >= N) return;
    dis[v] = rsqrtf((float)deg[v] + 1.0f);
}

// ---- exclusive scan over deg -> rowptr (3-kernel) -------------------------
__global__ void scan_block_kernel(const int* __restrict__ deg, int* __restrict__ rowptr,
                                  int* __restrict__ aux, int N) {
    __shared__ int s[256];
    int i = blockIdx.x * 256 + threadIdx.x;
    int v = (i < N) ? deg[i] : 0;
    s[threadIdx.x] = v;
    __syncthreads();
    for (int off = 1; off < 256; off <<= 1) {
        int t = (threadIdx.x >= off) ? s[threadIdx.x - off] : 0;
        __syncthreads();
        s[threadIdx.x] += t;
        __syncthreads();
    }
    if (i < N) rowptr[i] = s[threadIdx.x] - v;
    if (threadIdx.x == 255) aux[blockIdx.x] = s[255];
}

__global__ void scan_aux_kernel(int* __restrict__ aux, int nb) {
    __shared__ int s[256];
    int i = threadIdx.x;
    int v = (i < nb) ? aux[i] : 0;
    s[i] = v;
    __syncthreads();
    for (int off = 1; off < 256; off <<= 1) {
        int t = (i >= off) ? s[i - off] : 0;
        __syncthreads();
        s[i] += t;
        __syncthreads();
    }
    if (i < nb) aux[i] = s[i] - v;
}

__global__ void add_offsets_kernel(int* __restrict__ rowptr, const int* __restrict__ aux,
                                   int N, int E) {
    int i = blockIdx.x * 256 + threadIdx.x;
    if (i < N) rowptr[i] += aux[i >> 8];
    if (i == 0) rowptr[N] = E;
}

// ---- CSR fill (src only; weights recomputed on the fly in propagate) ------
__global__ void fill_csr_kernel(const int* __restrict__ ew, const int* __restrict__ mode_p,
                                const int* __restrict__ rowptr, int* __restrict__ cursor,
                                int* __restrict__ csr_src, int E) {
    int e = blockIdx.x * blockDim.x + threadIdx.x;
    if (e >= E) return;
    int mode = *mode_p;
    int s = load_src(ew, mode, e, E);
    int d = load_dst(ew, mode, e, E);
    int pos = rowptr[d] + atomicAdd(&cursor[d], 1);
    csr_src[pos] = s;
}

// ---- W (KxM f32) -> transposed split Bt_hi/Bt_lo (u16 [M][K]) -------------
__global__ void conv_w_kernel(const float* __restrict__ W, u16* __restrict__ hi,
                              u16* __restrict__ lo, int K, int M) {
    int idx = blockIdx.x * blockDim.x + threadIdx.x;
    if (idx >= K * M) return;
    int k = idx / M, n = idx % M;
    u16 h, l;
    split_bf16(W[idx], h, l);
    hi[n * K + k] = h;
    lo[n * K + k] = l;
}

// ---- [Wm | Ws] (128x64 each) -> transposed split [128][128] ---------------
__global__ void conv_wcat_kernel(const float* __restrict__ Wm, const float* __restrict__ Ws,
                                 u16* __restrict__ hi, u16* __restrict__ lo) {
    int idx = blockIdx.x * blockDim.x + threadIdx.x; // K=128 x M=128
    if (idx >= 128 * 128) return;
    int k = idx >> 7, j = idx & 127;
    float f = (j < 64) ? Wm[k * 64 + j] : Ws[k * 64 + (j - 64)];
    u16 h, l;
    split_bf16(f, h, l);
    hi[j * 128 + k] = h;
    lo[j * 128 + k] = l;
}

// ---- MFMA GEMM: C[N x 128] = A[N x K] @ B[K x 128] (B given split+T) ------
// Tile 64 rows x 128 cols, 4 waves, each wave 32x64 (2x4 MFMA 16x16 tiles).
// Split bf16: acc += Ahi*Bhi + Ahi*Blo + Alo*Bhi (error ~2^-16 relative).
__global__ __launch_bounds__(256) void gemm_mfma(const float* __restrict__ A,
                                                 const u16* __restrict__ Bt_hi,
                                                 const u16* __restrict__ Bt_lo,
                                                 float* __restrict__ C,
                                                 int N, int K) {
    __shared__ u16 As[2][64][40];   // [hi/lo][row][k], stride 40 => 16B-aligned frags
    __shared__ u16 Bs[2][128][40];  // [hi/lo][n][k]

    const int tid = threadIdx.x;
    const int row0 = blockIdx.y * 64;

    // staging indices
    const int ar = tid >> 2;           // 0..63 row in tile
    const int ak = (tid & 3) * 8;      // 0,8,16,24
    const int bn = tid >> 1;           // 0..127 col(n)
    const int bk = (tid & 1) * 16;     // 0 or 16

    // compute indices
    const int w = tid >> 6;
    const int lane = tid & 63;
    const int R = (w >> 1) * 32;       // wave row offset
    const int Cc = (w & 1) * 64;       // wave col offset
    const int m16 = lane & 15;
    const int quad = lane >> 4;
    const int koff = quad * 8;

    f32x4 acc[2][4];
#pragma unroll
    for (int i = 0; i < 2; ++i)
#pragma unroll
        for (int j = 0; j < 4; ++j) acc[i][j] = (f32x4)0.f;

    const int grow = row0 + ar;
    const bool arow_ok = (grow < N);
    const float* aptr = A + (size_t)grow * K;

    // ---- preload first K-slice into registers ----
    float av[8];
    short8 bh0, bh1, bl0, bl1;
    {
        f32x4 v0 = (f32x4)0.f, v1 = (f32x4)0.f;
        if (arow_ok) {
            v0 = *(const f32x4*)&aptr[ak];
            v1 = *(const f32x4*)&aptr[ak + 4];
        }
#pragma unroll
        for (int q = 0; q < 4; ++q) { av[q] = v0[q]; av[4 + q] = v1[q]; }
        const size_t bo = (size_t)bn * K + bk;
        bh0 = *(const short8*)&Bt_hi[bo];
        bh1 = *(const short8*)&Bt_hi[bo + 8];
        bl0 = *(const short8*)&Bt_lo[bo];
        bl1 = *(const short8*)&Bt_lo[bo + 8];
    }

    const int ksteps = K >> 5;
    for (int ks = 0; ks < ksteps; ++ks) {
        // convert A regs to hi/lo
        short8 ah, al;
#pragma unroll
        for (int q = 0; q < 8; ++q) {
            u16 h, l;
            split_bf16(av[q], h, l);
            ah[q] = (short)h;
            al[q] = (short)l;
        }
        __syncthreads();   // previous compute done before overwrite
        *(short8*)&As[0][ar][ak] = ah;
        *(short8*)&As[1][ar][ak] = al;
        *(short8*)&Bs[0][bn][bk] = bh0;
        *(short8*)&Bs[0][bn][bk + 8] = bh1;
        *(short8*)&Bs[1][bn][bk] = bl0;
        *(short8*)&Bs[1][bn][bk + 8] = bl1;
        __syncthreads();

        // prefetch next K-slice while computing
        if (ks + 1 < ksteps) {
            const int k0 = (ks + 1) * 32;
            f32x4 v0 = (f32x4)0.f, v1 = (f32x4)0.f;
            if (arow_ok) {
                v0 = *(const f32x4*)&aptr[k0 + ak];
                v1 = *(const f32x4*)&aptr[k0 + ak + 4];
            }
#pragma unroll
            for (int q = 0; q < 4; ++q) { av[q] = v0[q]; av[4 + q] = v1[q]; }
            const size_t bo = (size_t)bn * K + k0 + bk;
            bh0 = *(const short8*)&Bt_hi[bo];
            bh1 = *(const short8*)&Bt_hi[bo + 8];
            bl0 = *(const short8*)&Bt_lo[bo];
            bl1 = *(const short8*)&Bt_lo[bo + 8];
        }

        // fragment loads
        short8 fa_h[2], fa_l[2], fb_h[4], fb_l[4];
#pragma unroll
        for (int i = 0; i < 2; ++i) {
            fa_h[i] = *(const short8*)&As[0][R + i * 16 + m16][koff];
            fa_l[i] = *(const short8*)&As[1][R + i * 16 + m16][koff];
        }
#pragma unroll
        for (int j = 0; j < 4; ++j) {
            fb_h[j] = *(const short8*)&Bs[0][Cc + j * 16 + m16][koff];
            fb_l[j] = *(const short8*)&Bs[1][Cc + j * 16 + m16][koff];
        }
#pragma unroll
        for (int i = 0; i < 2; ++i)
#pragma unroll
            for (int j = 0; j < 4; ++j) {
                acc[i][j] = __builtin_amdgcn_mfma_f32_16x16x32_bf16(
                    fa_h[i], fb_h[j], acc[i][j], 0, 0, 0);
                acc[i][j] = __builtin_amdgcn_mfma_f32_16x16x32_bf16(
                    fa_h[i], fb_l[j], acc[i][j], 0, 0, 0);
                acc[i][j] = __builtin_amdgcn_mfma_f32_16x16x32_bf16(
                    fa_l[i], fb_h[j], acc[i][j], 0, 0, 0);
            }
    }

    // epilogue: C/D layout col=lane&15, row=quad*4+reg
#pragma unroll
    for (int i = 0; i < 2; ++i) {
#pragma unroll
        for (int r = 0; r < 4; ++r) {
            int gr = row0 + R + i * 16 + quad * 4 + r;
            if (gr < N) {
#pragma unroll
                for (int j = 0; j < 4; ++j)
                    C[(size_t)gr * 128 + Cc + j * 16 + m16] = acc[i][j][r];
            }
        }
    }
}

// ---- propagate (one wave per node, 128 feats = 2/lane), +bias, opt ReLU ---
// Edge weight dis[s]*dis[v] recomputed on the fly (wave-uniform loads).
__global__ __launch_bounds__(256) void propagate_kernel(
    const float* __restrict__ h, const int* __restrict__ rowptr,
    const int* __restrict__ csr_src, const float* __restrict__ dis,
    const float* __restrict__ bias, float* __restrict__ out, int N, int do_relu) {
    int wave = (blockIdx.x * 256 + threadIdx.x) >> 6;
    int lane = threadIdx.x & 63;
    if (wave >= N) return;
    int v = wave;
    int f = lane * 2;
    float dv = dis[v];
    float ax = 0.f, ay = 0.f;
    int beg = rowptr[v], end = rowptr[v + 1];
    for (int i = beg; i < end; ++i) {
        int s = csr_src[i];
        float w = dis[s] * dv;
        float2 hv = *(const float2*)&h[(size_t)s * 128 + f];
        ax += w * hv.x;
        ay += w * hv.y;
    }
    float2 hv = *(const float2*)&h[(size_t)v * 128 + f];
    ax += dv * dv * hv.x;
    ay += dv * dv * hv.y;
    ax += bias[f];
    ay += bias[f + 1];
    if (do_relu) { ax = fmaxf(ax, 0.f); ay = fmaxf(ay, 0.f); }
    *(float2*)&out[(size_t)v * 128 + f] = make_float2(ax, ay);
}

// ---- final propagate: split into z_mean / z_log_std -----------------------
__global__ __launch_bounds__(256) void propagate_final_kernel(
    const float* __restrict__ h, const int* __restrict__ rowptr,
    const int* __restrict__ csr_src, const float* __restrict__ dis,
    const float* __restrict__ bm, const float* __restrict__ bs,
    float* __restrict__ out, int N) {
    int wave = (blockIdx.x * 256 + threadIdx.x) >> 6;
    int lane = threadIdx.x & 63;
    if (wave >= N) return;
    int v = wave;
    int f = lane * 2;
    float dv = dis[v];
    float ax = 0.f, ay = 0.f;
    int beg = rowptr[v], end = rowptr[v + 1];
    for (int i = beg; i < end; ++i) {
        int s = csr_src[i];
        float w = dis[s] * dv;
        float2 hv = *(const float2*)&h[(size_t)s * 128 + f];
        ax += w * hv.x;
        ay += w * hv.y;
    }
    float2 hv = *(const float2*)&h[(size_t)v * 128 + f];
    ax += dv * dv * hv.x;
    ay += dv * dv * hv.y;
    if (f < 64) {
        *(float2*)&out[(size_t)v * 64 + f] = make_float2(ax + bm[f], ay + bm[f + 1]);
    } else {
        int g = f - 64;
        *(float2*)&out[(size_t)N * 64 + (size_t)v * 64 + g] =
            make_float2(ax + bs[g], ay + bs[g + 1]);
    }
}

extern "C" void kernel_launch(void* const* d_in, const int* in_sizes, int n_in,
                              void* d_out, int out_size, void* d_ws, size_t ws_size,
                              hipStream_t stream) {
    const float* x  = (const float*)d_in[0];
    const int*   ew = (const int*)d_in[1];
    const float* W1 = (const float*)d_in[2];
    const float* b1 = (const float*)d_in[3];
    const float* W2 = (const float*)d_in[4];
    const float* b2 = (const float*)d_in[5];
    const float* Wm = (const float*)d_in[6];
    const float* bm = (const float*)d_in[7];
    const float* Ws = (const float*)d_in[8];
    const float* bs = (const float*)d_in[9];
    float* out = (float*)d_out;

    const int IN = 512, H = 128;
    const int N = in_sizes[0] / IN;     // 50000
    const int E = in_sizes[1] / 2;      // 800000

    // ---- workspace layout: total 55,202,048 B (< proven-safe 58,467,584) ---
    char* base = (char*)d_ws;
    size_t off = 0;
    auto alloc = [&](size_t bytes) -> char* {
        char* p = base + off;
        off = (off + bytes + 255) & ~(size_t)255;
        return p;
    };
    int*   mode_p  = (int*)  alloc(4);
    char*  regionA = (char*) alloc(400384);            // union (see below)
    float* dis     = (float*)alloc((size_t)N * 4);
    int*   rowptr  = (int*)  alloc((size_t)(N + 1) * 4);
    int*   aux     = (int*)  alloc(256 * 4);
    int*   csr_src = (int*)  alloc((size_t)E * 4);
    float* hA      = (float*)alloc((size_t)N * H * 4);
    float* hB      = (float*)alloc((size_t)N * H * 4);
    (void)ws_size; (void)n_in; (void)out_size;

    // regionA phase 1: deg + cursor (dead after fill_csr)
    int* deg    = (int*)regionA;
    int* cursor = (int*)(regionA + 200192);
    // regionA phase 2: W splits (written after fill_csr, stream-ordered)
    u16* W1t_hi = (u16*)(regionA);            // 131072 B
    u16* W1t_lo = (u16*)(regionA + 131072);   // 131072 B
    u16* W2t_hi = (u16*)(regionA + 262144);   //  32768 B
    u16* W2t_lo = (u16*)(regionA + 294912);   //  32768 B
    u16* Wct_hi = (u16*)(regionA + 327680);   //  32768 B
    u16* Wct_lo = (u16*)(regionA + 360448);   //  32768 B -> ends 393216 <= 400384

    hipMemsetAsync(regionA, 0, 400384, stream);   // zero deg + cursor

    const int eblocks = (E + 255) / 256;
    const int nblocks = (N + 255) / 256;

    detect_mode_kernel<<<1, 256, 0, stream>>>(ew, mode_p);
    deg_kernel<<<eblocks, 256, 0, stream>>>(ew, mode_p, deg, E);
    dis_kernel<<<nblocks, 256, 0, stream>>>(deg, dis, N);
    scan_block_kernel<<<nblocks, 256, 0, stream>>>(deg, rowptr, aux, N);
    scan_aux_kernel<<<1, 256, 0, stream>>>(aux, nblocks);
    add_offsets_kernel<<<nblocks, 256, 0, stream>>>(rowptr, aux, N, E);
    fill_csr_kernel<<<eblocks, 256, 0, stream>>>(ew, mode_p, rowptr, cursor,
                                                 csr_src, E);
    // deg/cursor dead from here; regionA becomes W-split storage
    conv_w_kernel<<<(IN * H + 255) / 256, 256, 0, stream>>>(W1, W1t_hi, W1t_lo, IN, H);
    conv_w_kernel<<<(H * H + 255) / 256, 256, 0, stream>>>(W2, W2t_hi, W2t_lo, H, H);
    conv_wcat_kernel<<<(H * H + 255) / 256, 256, 0, stream>>>(Wm, Ws, Wct_hi, Wct_lo);

    dim3 gg(1, (N + 63) / 64);
    const int pblocks = (N * 64 + 255) / 256;

    gemm_mfma<<<gg, 256, 0, stream>>>(x, W1t_hi, W1t_lo, hA, N, IN);
    propagate_kernel<<<pblocks, 256, 0, stream>>>(hA, rowptr, csr_src, dis,
                                                  b1, hB, N, 1);
    gemm_mfma<<<gg, 256, 0, stream>>>(hB, W2t_hi, W2t_lo, hA, N, H);
    propagate_kernel<<<pblocks, 256, 0, stream>>>(hA, rowptr, csr_src, dis,
                                                  b2, hB, N, 1);
    gemm_mfma<<<gg, 256, 0, stream>>>(hB, Wct_hi, Wct_lo, hA, N, H);
    propagate_final_kernel<<<pblocks, 256, 0, stream>>>(hA, rowptr, csr_src, dis,
                                                        bm, bs, out, N);
}

// Round 4
// 504.386 us; speedup vs baseline: 1.3040x; 1.1626x over previous
//
#include <hip/hip_runtime.h>

// ---------------------------------------------------------------------------
// CellVGAE GCN encoder: x -> GCN(512,128)+ReLU -> GCN(128,128)+ReLU
//                         -> {GCN(128,64) mean, GCN(128,64) log_std}
// Round 4: propagate edge-loop unrolled x4 (4 independent 512B gathers in
// flight per wave). Round-3 profile showed propagates latency-bound:
// hbm 2.37 TB/s, VALU 14%, serial dependent gather chain.
// ---------------------------------------------------------------------------

using u16 = unsigned short;
typedef __attribute__((ext_vector_type(8))) short short8;
typedef __attribute__((ext_vector_type(4))) float f32x4;

__device__ __forceinline__ void split_bf16(float f, u16& hi, u16& lo) {
    unsigned b = __float_as_uint(f);
    hi = (u16)(b >> 16);
    float rem = f - __uint_as_float(b & 0xFFFF0000u);
    lo = (u16)(__float_as_uint(rem) >> 16);
}

// ---- mode detect: is edge_index int64 (1) or int32 (0)? -------------------
__global__ void detect_mode_kernel(const int* __restrict__ ew, int* __restrict__ mode_p) {
    __shared__ int flag;
    if (threadIdx.x == 0) flag = 0;
    __syncthreads();
    int nz = 0;
    for (int i = threadIdx.x; i < 1024; i += 256)
        nz |= (ew[2 * i + 1] != 0);
    if (nz) atomicOr(&flag, 1);
    __syncthreads();
    if (threadIdx.x == 0) *mode_p = flag ? 0 : 1;   // 1 = int64, 0 = int32
}

__device__ __forceinline__ int load_src(const int* ew, int mode, int e, int E) {
    return mode ? ew[2 * e] : ew[e];
}
__device__ __forceinline__ int load_dst(const int* ew, int mode, int e, int E) {
    return mode ? ew[2 * E + 2 * e] : ew[E + e];
}

// ---- degree count ---------------------------------------------------------
__global__ void deg_kernel(const int* __restrict__ ew, const int* __restrict__ mode_p,
                           int* __restrict__ deg, int E) {
    int e = blockIdx.x * blockDim.x + threadIdx.x;
    if (e >= E) return;
    int mode = *mode_p;
    int d = load_dst(ew, mode, e, E);
    atomicAdd(&deg[d], 1);
}

// ---- dis = rsqrt(deg + 1)  (self-loop included) ---------------------------
__global__ void dis_kernel(const int* __restrict__ deg, float* __restrict__ dis, int N) {
    int v = blockIdx.x * blockDim.x + threadIdx.x;
    if (v >= N) return;
    dis[v] = rsqrtf((float)deg[v] + 1.0f);
}

// ---- exclusive scan over deg -> rowptr (3-kernel) -------------------------
__global__ void scan_block_kernel(const int* __restrict__ deg, int* __restrict__ rowptr,
                                  int* __restrict__ aux, int N) {
    __shared__ int s[256];
    int i = blockIdx.x * 256 + threadIdx.x;
    int v = (i < N) ? deg[i] : 0;
    s[threadIdx.x] = v;
    __syncthreads();
    for (int off = 1; off < 256; off <<= 1) {
        int t = (threadIdx.x >= off) ? s[threadIdx.x - off] : 0;
        __syncthreads();
        s[threadIdx.x] += t;
        __syncthreads();
    }
    if (i < N) rowptr[i] = s[threadIdx.x] - v;
    if (threadIdx.x == 255) aux[blockIdx.x] = s[255];
}

__global__ void scan_aux_kernel(int* __restrict__ aux, int nb) {
    __shared__ int s[256];
    int i = threadIdx.x;
    int v = (i < nb) ? aux[i] : 0;
    s[i] = v;
    __syncthreads();
    for (int off = 1; off < 256; off <<= 1) {
        int t = (i >= off) ? s[i - off] : 0;
        __syncthreads();
        s[i] += t;
        __syncthreads();
    }
    if (i < nb) aux[i] = s[i] - v;
}

__global__ void add_offsets_kernel(int* __restrict__ rowptr, const int* __restrict__ aux,
                                   int N, int E) {
    int i = blockIdx.x * 256 + threadIdx.x;
    if (i < N) rowptr[i] += aux[i >> 8];
    if (i == 0) rowptr[N] = E;
}

// ---- CSR fill (src only; weights recomputed on the fly in propagate) ------
__global__ void fill_csr_kernel(const int* __restrict__ ew, const int* __restrict__ mode_p,
                                const int* __restrict__ rowptr, int* __restrict__ cursor,
                                int* __restrict__ csr_src, int E) {
    int e = blockIdx.x * blockDim.x + threadIdx.x;
    if (e >= E) return;
    int mode = *mode_p;
    int s = load_src(ew, mode, e, E);
    int d = load_dst(ew, mode, e, E);
    int pos = rowptr[d] + atomicAdd(&cursor[d], 1);
    csr_src[pos] = s;
}

// ---- W (KxM f32) -> transposed split Bt_hi/Bt_lo (u16 [M][K]) -------------
__global__ void conv_w_kernel(const float* __restrict__ W, u16* __restrict__ hi,
                              u16* __restrict__ lo, int K, int M) {
    int idx = blockIdx.x * blockDim.x + threadIdx.x;
    if (idx >= K * M) return;
    int k = idx / M, n = idx % M;
    u16 h, l;
    split_bf16(W[idx], h, l);
    hi[n * K + k] = h;
    lo[n * K + k] = l;
}

// ---- [Wm | Ws] (128x64 each) -> transposed split [128][128] ---------------
__global__ void conv_wcat_kernel(const float* __restrict__ Wm, const float* __restrict__ Ws,
                                 u16* __restrict__ hi, u16* __restrict__ lo) {
    int idx = blockIdx.x * blockDim.x + threadIdx.x; // K=128 x M=128
    if (idx >= 128 * 128) return;
    int k = idx >> 7, j = idx & 127;
    float f = (j < 64) ? Wm[k * 64 + j] : Ws[k * 64 + (j - 64)];
    u16 h, l;
    split_bf16(f, h, l);
    hi[j * 128 + k] = h;
    lo[j * 128 + k] = l;
}

// ---- MFMA GEMM: C[N x 128] = A[N x K] @ B[K x 128] (B given split+T) ------
__global__ __launch_bounds__(256) void gemm_mfma(const float* __restrict__ A,
                                                 const u16* __restrict__ Bt_hi,
                                                 const u16* __restrict__ Bt_lo,
                                                 float* __restrict__ C,
                                                 int N, int K) {
    __shared__ u16 As[2][64][40];
    __shared__ u16 Bs[2][128][40];

    const int tid = threadIdx.x;
    const int row0 = blockIdx.y * 64;

    const int ar = tid >> 2;
    const int ak = (tid & 3) * 8;
    const int bn = tid >> 1;
    const int bk = (tid & 1) * 16;

    const int w = tid >> 6;
    const int lane = tid & 63;
    const int R = (w >> 1) * 32;
    const int Cc = (w & 1) * 64;
    const int m16 = lane & 15;
    const int quad = lane >> 4;
    const int koff = quad * 8;

    f32x4 acc[2][4];
#pragma unroll
    for (int i = 0; i < 2; ++i)
#pragma unroll
        for (int j = 0; j < 4; ++j) acc[i][j] = (f32x4)0.f;

    const int grow = row0 + ar;
    const bool arow_ok = (grow < N);
    const float* aptr = A + (size_t)grow * K;

    float av[8];
    short8 bh0, bh1, bl0, bl1;
    {
        f32x4 v0 = (f32x4)0.f, v1 = (f32x4)0.f;
        if (arow_ok) {
            v0 = *(const f32x4*)&aptr[ak];
            v1 = *(const f32x4*)&aptr[ak + 4];
        }
#pragma unroll
        for (int q = 0; q < 4; ++q) { av[q] = v0[q]; av[4 + q] = v1[q]; }
        const size_t bo = (size_t)bn * K + bk;
        bh0 = *(const short8*)&Bt_hi[bo];
        bh1 = *(const short8*)&Bt_hi[bo + 8];
        bl0 = *(const short8*)&Bt_lo[bo];
        bl1 = *(const short8*)&Bt_lo[bo + 8];
    }

    const int ksteps = K >> 5;
    for (int ks = 0; ks < ksteps; ++ks) {
        short8 ah, al;
#pragma unroll
        for (int q = 0; q < 8; ++q) {
            u16 h, l;
            split_bf16(av[q], h, l);
            ah[q] = (short)h;
            al[q] = (short)l;
        }
        __syncthreads();
        *(short8*)&As[0][ar][ak] = ah;
        *(short8*)&As[1][ar][ak] = al;
        *(short8*)&Bs[0][bn][bk] = bh0;
        *(short8*)&Bs[0][bn][bk + 8] = bh1;
        *(short8*)&Bs[1][bn][bk] = bl0;
        *(short8*)&Bs[1][bn][bk + 8] = bl1;
        __syncthreads();

        if (ks + 1 < ksteps) {
            const int k0 = (ks + 1) * 32;
            f32x4 v0 = (f32x4)0.f, v1 = (f32x4)0.f;
            if (arow_ok) {
                v0 = *(const f32x4*)&aptr[k0 + ak];
                v1 = *(const f32x4*)&aptr[k0 + ak + 4];
            }
#pragma unroll
            for (int q = 0; q < 4; ++q) { av[q] = v0[q]; av[4 + q] = v1[q]; }
            const size_t bo = (size_t)bn * K + k0 + bk;
            bh0 = *(const short8*)&Bt_hi[bo];
            bh1 = *(const short8*)&Bt_hi[bo + 8];
            bl0 = *(const short8*)&Bt_lo[bo];
            bl1 = *(const short8*)&Bt_lo[bo + 8];
        }

        short8 fa_h[2], fa_l[2], fb_h[4], fb_l[4];
#pragma unroll
        for (int i = 0; i < 2; ++i) {
            fa_h[i] = *(const short8*)&As[0][R + i * 16 + m16][koff];
            fa_l[i] = *(const short8*)&As[1][R + i * 16 + m16][koff];
        }
#pragma unroll
        for (int j = 0; j < 4; ++j) {
            fb_h[j] = *(const short8*)&Bs[0][Cc + j * 16 + m16][koff];
            fb_l[j] = *(const short8*)&Bs[1][Cc + j * 16 + m16][koff];
        }
#pragma unroll
        for (int i = 0; i < 2; ++i)
#pragma unroll
            for (int j = 0; j < 4; ++j) {
                acc[i][j] = __builtin_amdgcn_mfma_f32_16x16x32_bf16(
                    fa_h[i], fb_h[j], acc[i][j], 0, 0, 0);
                acc[i][j] = __builtin_amdgcn_mfma_f32_16x16x32_bf16(
                    fa_h[i], fb_l[j], acc[i][j], 0, 0, 0);
                acc[i][j] = __builtin_amdgcn_mfma_f32_16x16x32_bf16(
                    fa_l[i], fb_h[j], acc[i][j], 0, 0, 0);
            }
    }

#pragma unroll
    for (int i = 0; i < 2; ++i) {
#pragma unroll
        for (int r = 0; r < 4; ++r) {
            int gr = row0 + R + i * 16 + quad * 4 + r;
            if (gr < N) {
#pragma unroll
                for (int j = 0; j < 4; ++j)
                    C[(size_t)gr * 128 + Cc + j * 16 + m16] = acc[i][j][r];
            }
        }
    }
}

// ---- propagate (one wave per node, 128 feats = 2/lane), +bias, opt ReLU ---
// Edge loop unrolled x4: 4 independent gathers in flight per wave (MLP).
__global__ __launch_bounds__(256) void propagate_kernel(
    const float* __restrict__ h, const int* __restrict__ rowptr,
    const int* __restrict__ csr_src, const float* __restrict__ dis,
    const float* __restrict__ bias, float* __restrict__ out, int N, int do_relu) {
    int wave = (blockIdx.x * 256 + threadIdx.x) >> 6;
    int lane = threadIdx.x & 63;
    if (wave >= N) return;
    int v = wave;
    int f = lane * 2;
    float dv = dis[v];
    float ax = 0.f, ay = 0.f;
    int beg = rowptr[v], end = rowptr[v + 1];
    int i = beg;
    for (; i + 4 <= end; i += 4) {
        int s0 = csr_src[i + 0];
        int s1 = csr_src[i + 1];
        int s2 = csr_src[i + 2];
        int s3 = csr_src[i + 3];
        float w0 = dis[s0], w1 = dis[s1], w2 = dis[s2], w3 = dis[s3];
        float2 g0 = *(const float2*)&h[(size_t)s0 * 128 + f];
        float2 g1 = *(const float2*)&h[(size_t)s1 * 128 + f];
        float2 g2 = *(const float2*)&h[(size_t)s2 * 128 + f];
        float2 g3 = *(const float2*)&h[(size_t)s3 * 128 + f];
        w0 *= dv; w1 *= dv; w2 *= dv; w3 *= dv;
        ax += w0 * g0.x; ay += w0 * g0.y;
        ax += w1 * g1.x; ay += w1 * g1.y;
        ax += w2 * g2.x; ay += w2 * g2.y;
        ax += w3 * g3.x; ay += w3 * g3.y;
    }
    for (; i < end; ++i) {
        int s = csr_src[i];
        float ws = dis[s] * dv;
        float2 g = *(const float2*)&h[(size_t)s * 128 + f];
        ax += ws * g.x;
        ay += ws * g.y;
    }
    float2 hv = *(const float2*)&h[(size_t)v * 128 + f];
    ax += dv * dv * hv.x;
    ay += dv * dv * hv.y;
    ax += bias[f];
    ay += bias[f + 1];
    if (do_relu) { ax = fmaxf(ax, 0.f); ay = fmaxf(ay, 0.f); }
    *(float2*)&out[(size_t)v * 128 + f] = make_float2(ax, ay);
}

// ---- final propagate: split into z_mean / z_log_std -----------------------
__global__ __launch_bounds__(256) void propagate_final_kernel(
    const float* __restrict__ h, const int* __restrict__ rowptr,
    const int* __restrict__ csr_src, const float* __restrict__ dis,
    const float* __restrict__ bm, const float* __restrict__ bs,
    float* __restrict__ out, int N) {
    int wave = (blockIdx.x * 256 + threadIdx.x) >> 6;
    int lane = threadIdx.x & 63;
    if (wave >= N) return;
    int v = wave;
    int f = lane * 2;
    float dv = dis[v];
    float ax = 0.f, ay = 0.f;
    int beg = rowptr[v], end = rowptr[v + 1];
    int i = beg;
    for (; i + 4 <= end; i += 4) {
        int s0 = csr_src[i + 0];
        int s1 = csr_src[i + 1];
        int s2 = csr_src[i + 2];
        int s3 = csr_src[i + 3];
        float w0 = dis[s0], w1 = dis[s1], w2 = dis[s2], w3 = dis[s3];
        float2 g0 = *(const float2*)&h[(size_t)s0 * 128 + f];
        float2 g1 = *(const float2*)&h[(size_t)s1 * 128 + f];
        float2 g2 = *(const float2*)&h[(size_t)s2 * 128 + f];
        float2 g3 = *(const float2*)&h[(size_t)s3 * 128 + f];
        w0 *= dv; w1 *= dv; w2 *= dv; w3 *= dv;
        ax += w0 * g0.x; ay += w0 * g0.y;
        ax += w1 * g1.x; ay += w1 * g1.y;
        ax += w2 * g2.x; ay += w2 * g2.y;
        ax += w3 * g3.x; ay += w3 * g3.y;
    }
    for (; i < end; ++i) {
        int s = csr_src[i];
        float ws = dis[s] * dv;
        float2 g = *(const float2*)&h[(size_t)s * 128 + f];
        ax += ws * g.x;
        ay += ws * g.y;
    }
    float2 hv = *(const float2*)&h[(size_t)v * 128 + f];
    ax += dv * dv * hv.x;
    ay += dv * dv * hv.y;
    if (f < 64) {
        *(float2*)&out[(size_t)v * 64 + f] = make_float2(ax + bm[f], ay + bm[f + 1]);
    } else {
        int g = f - 64;
        *(float2*)&out[(size_t)N * 64 + (size_t)v * 64 + g] =
            make_float2(ax + bs[g], ay + bs[g + 1]);
    }
}

extern "C" void kernel_launch(void* const* d_in, const int* in_sizes, int n_in,
                              void* d_out, int out_size, void* d_ws, size_t ws_size,
                              hipStream_t stream) {
    const float* x  = (const float*)d_in[0];
    const int*   ew = (const int*)d_in[1];
    const float* W1 = (const float*)d_in[2];
    const float* b1 = (const float*)d_in[3];
    const float* W2 = (const float*)d_in[4];
    const float* b2 = (const float*)d_in[5];
    const float* Wm = (const float*)d_in[6];
    const float* bm = (const float*)d_in[7];
    const float* Ws = (const float*)d_in[8];
    const float* bs = (const float*)d_in[9];
    float* out = (float*)d_out;

    const int IN = 512, H = 128;
    const int N = in_sizes[0] / IN;     // 50000
    const int E = in_sizes[1] / 2;      // 800000

    // ---- workspace layout: total 55.2 MB (< proven-safe 58.47 MB) ----------
    char* base = (char*)d_ws;
    size_t off = 0;
    auto alloc = [&](size_t bytes) -> char* {
        char* p = base + off;
        off = (off + bytes + 255) & ~(size_t)255;
        return p;
    };
    int*   mode_p  = (int*)  alloc(4);
    char*  regionA = (char*) alloc(400384);
    float* dis     = (float*)alloc((size_t)N * 4);
    int*   rowptr  = (int*)  alloc((size_t)(N + 1) * 4);
    int*   aux     = (int*)  alloc(256 * 4);
    int*   csr_src = (int*)  alloc((size_t)E * 4);
    float* hA      = (float*)alloc((size_t)N * H * 4);
    float* hB      = (float*)alloc((size_t)N * H * 4);
    (void)ws_size; (void)n_in; (void)out_size;

    int* deg    = (int*)regionA;
    int* cursor = (int*)(regionA + 200192);
    u16* W1t_hi = (u16*)(regionA);
    u16* W1t_lo = (u16*)(regionA + 131072);
    u16* W2t_hi = (u16*)(regionA + 262144);
    u16* W2t_lo = (u16*)(regionA + 294912);
    u16* Wct_hi = (u16*)(regionA + 327680);
    u16* Wct_lo = (u16*)(regionA + 360448);

    hipMemsetAsync(regionA, 0, 400384, stream);

    const int eblocks = (E + 255) / 256;
    const int nblocks = (N + 255) / 256;

    detect_mode_kernel<<<1, 256, 0, stream>>>(ew, mode_p);
    deg_kernel<<<eblocks, 256, 0, stream>>>(ew, mode_p, deg, E);
    dis_kernel<<<nblocks, 256, 0, stream>>>(deg, dis, N);
    scan_block_kernel<<<nblocks, 256, 0, stream>>>(deg, rowptr, aux, N);
    scan_aux_kernel<<<1, 256, 0, stream>>>(aux, nblocks);
    add_offsets_kernel<<<nblocks, 256, 0, stream>>>(rowptr, aux, N, E);
    fill_csr_kernel<<<eblocks, 256, 0, stream>>>(ew, mode_p, rowptr, cursor,
                                                 csr_src, E);
    conv_w_kernel<<<(IN * H + 255) / 256, 256, 0, stream>>>(W1, W1t_hi, W1t_lo, IN, H);
    conv_w_kernel<<<(H * H + 255) / 256, 256, 0, stream>>>(W2, W2t_hi, W2t_lo, H, H);
    conv_wcat_kernel<<<(H * H + 255) / 256, 256, 0, stream>>>(Wm, Ws, Wct_hi, Wct_lo);

    dim3 gg(1, (N + 63) / 64);
    const int pblocks = (N * 64 + 255) / 256;

    gemm_mfma<<<gg, 256, 0, stream>>>(x, W1t_hi, W1t_lo, hA, N, IN);
    propagate_kernel<<<pblocks, 256, 0, stream>>>(hA, rowptr, csr_src, dis,
                                                  b1, hB, N, 1);
    gemm_mfma<<<gg, 256, 0, stream>>>(hB, W2t_hi, W2t_lo, hA, N, H);
    propagate_kernel<<<pblocks, 256, 0, stream>>>(hA, rowptr, csr_src, dis,
                                                  b2, hB, N, 1);
    gemm_mfma<<<gg, 256, 0, stream>>>(hB, Wct_hi, Wct_lo, hA, N, H);
    propagate_final_kernel<<<pblocks, 256, 0, stream>>>(hA, rowptr, csr_src, dis,
                                                        bm, bs, out, N);
}

// Round 5
// 499.519 us; speedup vs baseline: 1.3167x; 1.0097x over previous
//
#include <hip/hip_runtime.h>

// ---------------------------------------------------------------------------
// CellVGAE GCN encoder: x -> GCN(512,128)+ReLU -> GCN(128,128)+ReLU
//                         -> {GCN(128,64) mean, GCN(128,64) log_std}
// Round 5:
//  - GEMM: fragment-order LDS layout (lane*16B, tile stride 1040B) =>
//    conflict-free staging writes and frag reads (was 4.8M conflict cycles).
//  - Propagate: edge loop unrolled x8 (was x4) for deeper MLP.
//  - Fused: dis into scan_block, 3 weight-split kernels into 1, mode-detect
//    inlined into deg/fill (per-block ballot). 13 dispatches total.
// ---------------------------------------------------------------------------

using u16 = unsigned short;
typedef __attribute__((ext_vector_type(8))) short short8;
typedef __attribute__((ext_vector_type(4))) float f32x4;

__device__ __forceinline__ void split_bf16(float f, u16& hi, u16& lo) {
    unsigned b = __float_as_uint(f);
    hi = (u16)(b >> 16);
    float rem = f - __uint_as_float(b & 0xFFFF0000u);
    lo = (u16)(__float_as_uint(rem) >> 16);
}

// Block-wide mode detect: 1 = int64 edge_index, 0 = int32.
// Reads first 256 odd 32-bit words (high words if int64, all zero since
// values < 2^31; random node ids if int32 => ~surely nonzero somewhere).
// Must be called by ALL threads before any divergent exit.
__device__ __forceinline__ int block_mode(const int* __restrict__ ew, int* sflag) {
    if (threadIdx.x == 0) *sflag = 0;
    __syncthreads();
    if (ew[2 * (int)threadIdx.x + 1] != 0) atomicOr(sflag, 1);
    __syncthreads();
    return *sflag ? 0 : 1;
}

// ---- degree count (mode detect inlined) -----------------------------------
__global__ void deg_kernel(const int* __restrict__ ew, int* __restrict__ deg, int E) {
    __shared__ int sflag;
    int mode = block_mode(ew, &sflag);
    int e = blockIdx.x * blockDim.x + threadIdx.x;
    if (e >= E) return;
    int d = mode ? ew[2 * E + 2 * e] : ew[E + e];
    atomicAdd(&deg[d], 1);
}

// ---- exclusive scan over deg -> rowptr, fused dis = rsqrt(deg+1) ----------
__global__ void scan_block_kernel(const int* __restrict__ deg, int* __restrict__ rowptr,
                                  int* __restrict__ aux, float* __restrict__ dis, int N) {
    __shared__ int s[256];
    int i = blockIdx.x * 256 + threadIdx.x;
    int v = (i < N) ? deg[i] : 0;
    if (i < N) dis[i] = rsqrtf((float)v + 1.0f);
    s[threadIdx.x] = v;
    __syncthreads();
    for (int off = 1; off < 256; off <<= 1) {
        int t = (threadIdx.x >= off) ? s[threadIdx.x - off] : 0;
        __syncthreads();
        s[threadIdx.x] += t;
        __syncthreads();
    }
    if (i < N) rowptr[i] = s[threadIdx.x] - v;
    if (threadIdx.x == 255) aux[blockIdx.x] = s[255];
}

__global__ void scan_aux_kernel(int* __restrict__ aux, int nb) {
    __shared__ int s[256];
    int i = threadIdx.x;
    int v = (i < nb) ? aux[i] : 0;
    s[i] = v;
    __syncthreads();
    for (int off = 1; off < 256; off <<= 1) {
        int t = (i >= off) ? s[i - off] : 0;
        __syncthreads();
        s[i] += t;
        __syncthreads();
    }
    if (i < nb) aux[i] = s[i] - v;
}

__global__ void add_offsets_kernel(int* __restrict__ rowptr, const int* __restrict__ aux,
                                   int N, int E) {
    int i = blockIdx.x * 256 + threadIdx.x;
    if (i < N) rowptr[i] += aux[i >> 8];
    if (i == 0) rowptr[N] = E;
}

// ---- CSR fill (mode detect inlined) ---------------------------------------
__global__ void fill_csr_kernel(const int* __restrict__ ew,
                                const int* __restrict__ rowptr, int* __restrict__ cursor,
                                int* __restrict__ csr_src, int E) {
    __shared__ int sflag;
    int mode = block_mode(ew, &sflag);
    int e = blockIdx.x * blockDim.x + threadIdx.x;
    if (e >= E) return;
    int s = mode ? ew[2 * e] : ew[e];
    int d = mode ? ew[2 * E + 2 * e] : ew[E + e];
    int pos = rowptr[d] + atomicAdd(&cursor[d], 1);
    csr_src[pos] = s;
}

// ---- all weight transposed-splits in one kernel ---------------------------
__global__ void conv_all_kernel(const float* __restrict__ W1, const float* __restrict__ W2,
                                const float* __restrict__ Wm, const float* __restrict__ Ws,
                                u16* __restrict__ W1t_hi, u16* __restrict__ W1t_lo,
                                u16* __restrict__ W2t_hi, u16* __restrict__ W2t_lo,
                                u16* __restrict__ Wct_hi, u16* __restrict__ Wct_lo) {
    int idx = blockIdx.x * 256 + threadIdx.x;
    u16 h, l;
    if (idx < 65536) {                 // W1: 512x128 -> [128][512]
        int k = idx >> 7, n = idx & 127;
        split_bf16(W1[idx], h, l);
        W1t_hi[n * 512 + k] = h;
        W1t_lo[n * 512 + k] = l;
    } else if (idx < 81920) {          // W2: 128x128 -> [128][128]
        int t = idx - 65536;
        int k = t >> 7, n = t & 127;
        split_bf16(W2[t], h, l);
        W2t_hi[n * 128 + k] = h;
        W2t_lo[n * 128 + k] = l;
    } else if (idx < 98304) {          // [Wm|Ws]: 128x128 -> [128][128]
        int t = idx - 81920;
        int k = t >> 7, j = t & 127;
        float f = (j < 64) ? Wm[k * 64 + j] : Ws[k * 64 + (j - 64)];
        split_bf16(f, h, l);
        Wct_hi[j * 128 + k] = h;
        Wct_lo[j * 128 + k] = l;
    }
}

// ---- MFMA GEMM: C[N x 128] = A[N x K] @ B[K x 128] (B given split+T) ------
// Fragment-order LDS: tile t (16 rows/cols x 32 k) at t*520 u16; lane L's
// 16B fragment at base + L*8 u16. Tile stride 1040 B == bank skew +4.
// Staging maps chosen so LDS writes are lane-sequential (conflict-free).
#define TILE_OFF(t) ((t) * 520)

__global__ __launch_bounds__(256) void gemm_mfma(const float* __restrict__ A,
                                                 const u16* __restrict__ Bt_hi,
                                                 const u16* __restrict__ Bt_lo,
                                                 float* __restrict__ C,
                                                 int N, int K) {
    __shared__ u16 AsH[4 * 520], AsL[4 * 520];   // 64 rows
    __shared__ u16 BsH[8 * 520], BsL[8 * 520];   // 128 cols

    const int tid = threadIdx.x;
    const int w = tid >> 6, lane = tid & 63;
    const int row0 = blockIdx.y * 64;

    // A staging: wave w stages rows w*16..w*16+15; lane -> (row15, kq)
    const int s_ar = w * 16 + (lane & 15);       // tile row in [0,64)
    const int s_ak = (lane >> 4) * 8;            // k chunk 0,8,16,24
    const int a_dst = TILE_OFF(w) + lane * 8;    // sequential per wave
    // B staging: thread -> (col, khalf)
    const int s_bc = tid >> 1;                   // 0..127
    const int s_bk = (tid & 1) * 16;             // 0 or 16
    const int b_q0 = (tid & 1) * 2;
    const int b_dst0 = TILE_OFF(s_bc >> 4) + ((s_bc & 15) + 16 * (b_q0 + 0)) * 8;
    const int b_dst1 = TILE_OFF(s_bc >> 4) + ((s_bc & 15) + 16 * (b_q0 + 1)) * 8;

    // compute: wave tile = 32 rows x 64 cols
    const int R = (w >> 1) * 32, Cc = (w & 1) * 64;
    const int atile = (w >> 1) * 2;              // + i (0..1)
    const int btile = (w & 1) * 4;               // + j (0..3)
    const int m16 = lane & 15, quad = lane >> 4;

    f32x4 acc[2][4];
#pragma unroll
    for (int i = 0; i < 2; ++i)
#pragma unroll
        for (int j = 0; j < 4; ++j) acc[i][j] = (f32x4)0.f;

    const int grow = row0 + s_ar;
    const bool ok = (grow < N);
    const float* aptr = A + (size_t)grow * K + s_ak;
    const u16* bph = Bt_hi + (size_t)s_bc * K + s_bk;
    const u16* bpl = Bt_lo + (size_t)s_bc * K + s_bk;

    float av[8];
    short8 rbh0, rbh1, rbl0, rbl1;
    {
        f32x4 v0 = (f32x4)0.f, v1 = (f32x4)0.f;
        if (ok) { v0 = *(const f32x4*)&aptr[0]; v1 = *(const f32x4*)&aptr[4]; }
#pragma unroll
        for (int q = 0; q < 4; ++q) { av[q] = v0[q]; av[4 + q] = v1[q]; }
        rbh0 = *(const short8*)&bph[0];
        rbh1 = *(const short8*)&bph[8];
        rbl0 = *(const short8*)&bpl[0];
        rbl1 = *(const short8*)&bpl[8];
    }

    const int ksteps = K >> 5;
    for (int ks = 0; ks < ksteps; ++ks) {
        short8 ah, al;
#pragma unroll
        for (int q = 0; q < 8; ++q) {
            u16 h, l;
            split_bf16(av[q], h, l);
            ah[q] = (short)h;
            al[q] = (short)l;
        }
        __syncthreads();
        *(short8*)&AsH[a_dst] = ah;
        *(short8*)&AsL[a_dst] = al;
        *(short8*)&BsH[b_dst0] = rbh0;
        *(short8*)&BsH[b_dst1] = rbh1;
        *(short8*)&BsL[b_dst0] = rbl0;
        *(short8*)&BsL[b_dst1] = rbl1;
        __syncthreads();

        if (ks + 1 < ksteps) {
            const int k0 = (ks + 1) * 32;
            f32x4 v0 = (f32x4)0.f, v1 = (f32x4)0.f;
            if (ok) { v0 = *(const f32x4*)&aptr[k0]; v1 = *(const f32x4*)&aptr[k0 + 4]; }
#pragma unroll
            for (int q = 0; q < 4; ++q) { av[q] = v0[q]; av[4 + q] = v1[q]; }
            rbh0 = *(const short8*)&bph[k0];
            rbh1 = *(const short8*)&bph[k0 + 8];
            rbl0 = *(const short8*)&bpl[k0];
            rbl1 = *(const short8*)&bpl[k0 + 8];
        }

        short8 fa_h[2], fa_l[2], fb_h[4], fb_l[4];
#pragma unroll
        for (int i = 0; i < 2; ++i) {
            fa_h[i] = *(const short8*)&AsH[TILE_OFF(atile + i) + lane * 8];
            fa_l[i] = *(const short8*)&AsL[TILE_OFF(atile + i) + lane * 8];
        }
#pragma unroll
        for (int j = 0; j < 4; ++j) {
            fb_h[j] = *(const short8*)&BsH[TILE_OFF(btile + j) + lane * 8];
            fb_l[j] = *(const short8*)&BsL[TILE_OFF(btile + j) + lane * 8];
        }
#pragma unroll
        for (int i = 0; i < 2; ++i)
#pragma unroll
            for (int j = 0; j < 4; ++j) {
                acc[i][j] = __builtin_amdgcn_mfma_f32_16x16x32_bf16(
                    fa_h[i], fb_h[j], acc[i][j], 0, 0, 0);
                acc[i][j] = __builtin_amdgcn_mfma_f32_16x16x32_bf16(
                    fa_h[i], fb_l[j], acc[i][j], 0, 0, 0);
                acc[i][j] = __builtin_amdgcn_mfma_f32_16x16x32_bf16(
                    fa_l[i], fb_h[j], acc[i][j], 0, 0, 0);
            }
    }

    // epilogue: C/D layout col=lane&15, row=quad*4+reg
#pragma unroll
    for (int i = 0; i < 2; ++i) {
#pragma unroll
        for (int r = 0; r < 4; ++r) {
            int gr = row0 + R + i * 16 + quad * 4 + r;
            if (gr < N) {
#pragma unroll
                for (int j = 0; j < 4; ++j)
                    C[(size_t)gr * 128 + Cc + j * 16 + m16] = acc[i][j][r];
            }
        }
    }
}

// ---- propagate (one wave per node, 128 feats = 2/lane), unroll x8 ---------
__global__ __launch_bounds__(256) void propagate_kernel(
    const float* __restrict__ h, const int* __restrict__ rowptr,
    const int* __restrict__ csr_src, const float* __restrict__ dis,
    const float* __restrict__ bias, float* __restrict__ out, int N, int do_relu) {
    int wave = (blockIdx.x * 256 + threadIdx.x) >> 6;
    int lane = threadIdx.x & 63;
    if (wave >= N) return;
    int v = wave;
    int f = lane * 2;
    float dv = dis[v];
    float ax = 0.f, ay = 0.f;
    int beg = rowptr[v], end = rowptr[v + 1];
    int i = beg;
    for (; i + 8 <= end; i += 8) {
        int s[8];
        float ww[8];
        float2 g[8];
#pragma unroll
        for (int u = 0; u < 8; ++u) s[u] = csr_src[i + u];
#pragma unroll
        for (int u = 0; u < 8; ++u) ww[u] = dis[s[u]];
#pragma unroll
        for (int u = 0; u < 8; ++u) g[u] = *(const float2*)&h[(size_t)s[u] * 128 + f];
#pragma unroll
        for (int u = 0; u < 8; ++u) {
            float t = ww[u] * dv;
            ax += t * g[u].x;
            ay += t * g[u].y;
        }
    }
    if (i + 4 <= end) {
        int s[4];
        float ww[4];
        float2 g[4];
#pragma unroll
        for (int u = 0; u < 4; ++u) s[u] = csr_src[i + u];
#pragma unroll
        for (int u = 0; u < 4; ++u) ww[u] = dis[s[u]];
#pragma unroll
        for (int u = 0; u < 4; ++u) g[u] = *(const float2*)&h[(size_t)s[u] * 128 + f];
#pragma unroll
        for (int u = 0; u < 4; ++u) {
            float t = ww[u] * dv;
            ax += t * g[u].x;
            ay += t * g[u].y;
        }
        i += 4;
    }
    for (; i < end; ++i) {
        int s = csr_src[i];
        float ws = dis[s] * dv;
        float2 g = *(const float2*)&h[(size_t)s * 128 + f];
        ax += ws * g.x;
        ay += ws * g.y;
    }
    float2 hv = *(const float2*)&h[(size_t)v * 128 + f];
    ax += dv * dv * hv.x;
    ay += dv * dv * hv.y;
    ax += bias[f];
    ay += bias[f + 1];
    if (do_relu) { ax = fmaxf(ax, 0.f); ay = fmaxf(ay, 0.f); }
    *(float2*)&out[(size_t)v * 128 + f] = make_float2(ax, ay);
}

// ---- final propagate: split into z_mean / z_log_std -----------------------
__global__ __launch_bounds__(256) void propagate_final_kernel(
    const float* __restrict__ h, const int* __restrict__ rowptr,
    const int* __restrict__ csr_src, const float* __restrict__ dis,
    const float* __restrict__ bm, const float* __restrict__ bs,
    float* __restrict__ out, int N) {
    int wave = (blockIdx.x * 256 + threadIdx.x) >> 6;
    int lane = threadIdx.x & 63;
    if (wave >= N) return;
    int v = wave;
    int f = lane * 2;
    float dv = dis[v];
    float ax = 0.f, ay = 0.f;
    int beg = rowptr[v], end = rowptr[v + 1];
    int i = beg;
    for (; i + 8 <= end; i += 8) {
        int s[8];
        float ww[8];
        float2 g[8];
#pragma unroll
        for (int u = 0; u < 8; ++u) s[u] = csr_src[i + u];
#pragma unroll
        for (int u = 0; u < 8; ++u) ww[u] = dis[s[u]];
#pragma unroll
        for (int u = 0; u < 8; ++u) g[u] = *(const float2*)&h[(size_t)s[u] * 128 + f];
#pragma unroll
        for (int u = 0; u < 8; ++u) {
            float t = ww[u] * dv;
            ax += t * g[u].x;
            ay += t * g[u].y;
        }
    }
    if (i + 4 <= end) {
        int s[4];
        float ww[4];
        float2 g[4];
#pragma unroll
        for (int u = 0; u < 4; ++u) s[u] = csr_src[i + u];
#pragma unroll
        for (int u = 0; u < 4; ++u) ww[u] = dis[s[u]];
#pragma unroll
        for (int u = 0; u < 4; ++u) g[u] = *(const float2*)&h[(size_t)s[u] * 128 + f];
#pragma unroll
        for (int u = 0; u < 4; ++u) {
            float t = ww[u] * dv;
            ax += t * g[u].x;
            ay += t * g[u].y;
        }
        i += 4;
    }
    for (; i < end; ++i) {
        int s = csr_src[i];
        float ws = dis[s] * dv;
        float2 g = *(const float2*)&h[(size_t)s * 128 + f];
        ax += ws * g.x;
        ay += ws * g.y;
    }
    float2 hv = *(const float2*)&h[(size_t)v * 128 + f];
    ax += dv * dv * hv.x;
    ay += dv * dv * hv.y;
    if (f < 64) {
        *(float2*)&out[(size_t)v * 64 + f] = make_float2(ax + bm[f], ay + bm[f + 1]);
    } else {
        int g = f - 64;
        *(float2*)&out[(size_t)N * 64 + (size_t)v * 64 + g] =
            make_float2(ax + bs[g], ay + bs[g + 1]);
    }
}

extern "C" void kernel_launch(void* const* d_in, const int* in_sizes, int n_in,
                              void* d_out, int out_size, void* d_ws, size_t ws_size,
                              hipStream_t stream) {
    const float* x  = (const float*)d_in[0];
    const int*   ew = (const int*)d_in[1];
    const float* W1 = (const float*)d_in[2];
    const float* b1 = (const float*)d_in[3];
    const float* W2 = (const float*)d_in[4];
    const float* b2 = (const float*)d_in[5];
    const float* Wm = (const float*)d_in[6];
    const float* bm = (const float*)d_in[7];
    const float* Ws = (const float*)d_in[8];
    const float* bs = (const float*)d_in[9];
    float* out = (float*)d_out;

    const int IN = 512, H = 128;
    const int N = in_sizes[0] / IN;     // 50000
    const int E = in_sizes[1] / 2;      // 800000

    // ---- workspace: ~55.6 MB total (< proven-safe 58.47 MB) ----------------
    char* base = (char*)d_ws;
    size_t off = 0;
    auto alloc = [&](size_t bytes) -> char* {
        char* p = base + off;
        off = (off + bytes + 255) & ~(size_t)255;
        return p;
    };
    char*  degcur  = (char*) alloc(400384);             // deg + cursor (zeroed)
    float* dis     = (float*)alloc((size_t)N * 4);
    int*   rowptr  = (int*)  alloc((size_t)(N + 1) * 4);
    int*   aux     = (int*)  alloc(256 * 4);
    int*   csr_src = (int*)  alloc((size_t)E * 4);
    u16*   W1t_hi  = (u16*)  alloc((size_t)IN * H * 2);
    u16*   W1t_lo  = (u16*)  alloc((size_t)IN * H * 2);
    u16*   W2t_hi  = (u16*)  alloc((size_t)H * H * 2);
    u16*   W2t_lo  = (u16*)  alloc((size_t)H * H * 2);
    u16*   Wct_hi  = (u16*)  alloc((size_t)H * H * 2);
    u16*   Wct_lo  = (u16*)  alloc((size_t)H * H * 2);
    float* hA      = (float*)alloc((size_t)N * H * 4);
    float* hB      = (float*)alloc((size_t)N * H * 4);
    (void)ws_size; (void)n_in; (void)out_size;

    int* deg    = (int*)degcur;
    int* cursor = (int*)(degcur + 200192);

    hipMemsetAsync(degcur, 0, 400384, stream);

    const int eblocks = (E + 255) / 256;
    const int nblocks = (N + 255) / 256;

    conv_all_kernel<<<(98304 + 255) / 256, 256, 0, stream>>>(
        W1, W2, Wm, Ws, W1t_hi, W1t_lo, W2t_hi, W2t_lo, Wct_hi, Wct_lo);
    deg_kernel<<<eblocks, 256, 0, stream>>>(ew, deg, E);
    scan_block_kernel<<<nblocks, 256, 0, stream>>>(deg, rowptr, aux, dis, N);
    scan_aux_kernel<<<1, 256, 0, stream>>>(aux, nblocks);
    add_offsets_kernel<<<nblocks, 256, 0, stream>>>(rowptr, aux, N, E);
    fill_csr_kernel<<<eblocks, 256, 0, stream>>>(ew, rowptr, cursor, csr_src, E);

    dim3 gg(1, (N + 63) / 64);
    const int pblocks = (N * 64 + 255) / 256;

    gemm_mfma<<<gg, 256, 0, stream>>>(x, W1t_hi, W1t_lo, hA, N, IN);
    propagate_kernel<<<pblocks, 256, 0, stream>>>(hA, rowptr, csr_src, dis,
                                                  b1, hB, N, 1);
    gemm_mfma<<<gg, 256, 0, stream>>>(hB, W2t_hi, W2t_lo, hA, N, H);
    propagate_kernel<<<pblocks, 256, 0, stream>>>(hA, rowptr, csr_src, dis,
                                                  b2, hB, N, 1);
    gemm_mfma<<<gg, 256, 0, stream>>>(hB, Wct_hi, Wct_lo, hA, N, H);
    propagate_final_kernel<<<pblocks, 256, 0, stream>>>(hA, rowptr, csr_src, dis,
                                                        bm, bs, out, N);
}